// Round 5
// baseline (3687.256 us; speedup 1.0000x reference)
//
#include <hip/hip_runtime.h>
#include <cstdint>

#define BX   32
#define NN   1000
#define FF   16
#define TT   48          // HIST + FC
#define HIST 24
#define FC   24
#define HID  64
#define DEG  16
#define GCIN 18          // F + 2
#define BN   (BX*NN)     // 32000 nodes
#define PADW 132         // ct row stride (floats): 132%32=4 -> 2-way b128 conflicts (free)
#define PADH 68          // dec h tile stride

__device__ __forceinline__ float sigf(float x)  { return 1.0f/(1.0f+__expf(-x)); }
__device__ __forceinline__ float tanhf_(float x){ return 2.0f/(1.0f+__expf(-2.0f*x)) - 1.0f; }

// ---------------- pre-pass: static part of the edge aggregation ----------------
// One block per (b,t): the 64KB X[b][t] slice is touched by exactly one block
// -> no cross-XCD L2 re-fetch. Threads stride the 1000 nodes.
__global__ __launch_bounds__(256, 2) void agg_pre(
    const float* __restrict__ X, const float* __restrict__ y,
    const int*   __restrict__ esrc, const float* __restrict__ ew,
    float* __restrict__ aggs)
{
    const int b = blockIdx.x;        // 0..31
    const int t = blockIdx.y;        // 0..23
    const float* Xt = X + (size_t)(b*TT + t)*NN*FF;
    const float* yt = y + (size_t)(b*TT + t)*NN;

    for (int nl = threadIdx.x; nl < NN; nl += 256){
        const int node = b*NN + nl;
        float agg[17];
        #pragma unroll
        for (int i=0;i<17;i++) agg[i]=0.f;

        const int e0 = node*DEG;
        const int4*   sv = (const int4*)  (esrc + e0);
        const float4* wv = (const float4*)(ew   + e0);
        #pragma unroll
        for (int q=0;q<4;q++){
            int4   s4 = sv[q];
            float4 w4 = wv[q];
            const int   ss[4] = {s4.x, s4.y, s4.z, s4.w};
            const float ww[4] = {w4.x, w4.y, w4.z, w4.w};
            #pragma unroll
            for (int i=0;i<4;i++){
                const int sl = ss[i] - b*NN;
                const float wgt = ww[i];
                agg[0] += wgt * yt[sl];
                const float4* sr = (const float4*)(Xt + sl*FF);
                #pragma unroll
                for (int q2=0;q2<4;q2++){
                    float4 v = sr[q2];
                    agg[1+4*q2] += wgt*v.x; agg[2+4*q2] += wgt*v.y;
                    agg[3+4*q2] += wgt*v.z; agg[4+4*q2] += wgt*v.w;
                }
            }
        }
        #pragma unroll
        for (int k=0;k<17;k++) aggs[((size_t)t*17 + k)*BN + node] = agg[k];
    }
}

// ---------------- encoder step ----------------
// block = 512 threads = 8 waves; 64 nodes/block (lane = node), wave = j-octet
// (8 of 64 hidden outputs). grid = 500 -> 4000 waves (~4 waves/SIMD).
// conv + h live in one LDS tile ct[lane][0:64)=conv, [64:128)=h; GEMV reads
// 16-float k-chunks as float4s; weights stream as contiguous s_load runs.
__global__ __launch_bounds__(512, 4) void enc_step(
    const float* __restrict__ X, const float* __restrict__ y,
    const int*   __restrict__ esrc, const float* __restrict__ ew,
    const float* __restrict__ aggs,
    const float* __restrict__ W_rel, const float* __restrict__ b_rel,
    const float* __restrict__ W_root,
    const float* __restrict__ Wih, const float* __restrict__ Whh,
    const float* __restrict__ bih, const float* __restrict__ bhh,
    const float* __restrict__ Wout, const float* __restrict__ bout,
    const float* __restrict__ h_in, float* __restrict__ h_out,
    const float* __restrict__ xn_in, float* __restrict__ xn_out,
    int t)
{
    __shared__ float ct[64][PADW];   // [lane][k]: k<64 conv, k in [64,128) h
    __shared__ float xs[8][64];

    const int lane = threadIdx.x & 63;
    int w = threadIdx.x >> 6;                   // 0..7
    w = __builtin_amdgcn_readfirstlane(w);      // wave-uniform -> s_load weights
    const int node = blockIdx.x*64 + lane;      // < 32000
    const int b    = node / NN;
    const int nloc = node - b*NN;

    const float* Xt = X + (size_t)(b*TT + t)*NN*FF;
    const float* yt = y + (size_t)(b*TT + t)*NN;

    // ---- stage h into LDS (8 k-rows per wave, coalesced global reads) ----
    #pragma unroll
    for (int i=0;i<8;i++){
        const int k = w*8 + i;
        ct[lane][64+k] = h_in[(size_t)k*BN + node];
    }

    // ---- own features xg = [xn, y, X] ----
    float xg[GCIN];
    xg[0] = xn_in[node];
    xg[1] = yt[nloc];
    {
        const float4* xr = (const float4*)(Xt + nloc*FF);
        #pragma unroll
        for (int q=0;q<4;q++){ float4 v = xr[q];
            xg[2+4*q]=v.x; xg[3+4*q]=v.y; xg[4+4*q]=v.z; xg[5+4*q]=v.w; }
    }

    // ---- aggregation: dynamic xn channel gathered, static channels loaded ----
    float agf[GCIN];
    {
        float a0 = 0.f;
        const int e0 = node*DEG;
        const int4*   sv = (const int4*)  (esrc + e0);
        const float4* wv = (const float4*)(ew   + e0);
        #pragma unroll
        for (int q=0;q<4;q++){
            int4   s4 = sv[q];
            float4 w4 = wv[q];
            a0 += w4.x * xn_in[s4.x];
            a0 += w4.y * xn_in[s4.y];
            a0 += w4.z * xn_in[s4.z];
            a0 += w4.w * xn_in[s4.w];
        }
        agf[0] = a0;
    }
    #pragma unroll
    for (int k=0;k<17;k++) agf[1+k] = aggs[((size_t)t*17 + k)*BN + node];

    // ---- GraphConv octet (8 outputs per wave) -> LDS ----
    const int j0 = w*8;
    {
        float c[8];
        #pragma unroll
        for (int j=0;j<8;j++) c[j] = b_rel[j0+j];
        #pragma unroll
        for (int k=0;k<GCIN;k++){
            const float* wr = W_rel  + k*HID + j0;
            const float* wo = W_root + k*HID + j0;
            #pragma unroll
            for (int j=0;j<8;j++) c[j] += agf[k]*wr[j] + xg[k]*wo[j];
        }
        #pragma unroll
        for (int j=0;j<8;j++) ct[lane][j0+j] = sigf(c[j]);
    }
    __syncthreads();

    // ---- GRU GEMV: 8 outputs/wave, 4 accumulators each ----
    float ar[8], az[8], ain[8], ahn[8];
    #pragma unroll
    for (int j=0;j<8;j++){
        const int jj = j0 + j;
        ar[j]  = bih[jj]     + bhh[jj];
        az[j]  = bih[64+jj]  + bhh[64+jj];
        ain[j] = bih[128+jj];
        ahn[j] = bhh[128+jj];
    }

    // xg part (k = 0..17 of the 82-wide Wih rows)
    #pragma unroll
    for (int j=0;j<8;j++){
        const int jj = j0 + j;
        const float* wr = Wih + (size_t) jj      *82;
        const float* wz = Wih + (size_t)(jj+ 64) *82;
        const float* wn = Wih + (size_t)(jj+128) *82;
        #pragma unroll
        for (int k=0;k<GCIN;k++){
            const float xv = xg[k];
            ar[j] += xv*wr[k]; az[j] += xv*wz[k]; ain[j] += xv*wn[k];
        }
    }

    // conv part: 4 chunks of 16 from LDS
    #pragma unroll
    for (int kc=0;kc<4;kc++){
        float ck[16];
        #pragma unroll
        for (int q=0;q<4;q++){
            float4 v = *(const float4*)&ct[lane][kc*16 + q*4];
            ck[q*4+0]=v.x; ck[q*4+1]=v.y; ck[q*4+2]=v.z; ck[q*4+3]=v.w;
        }
        #pragma unroll
        for (int j=0;j<8;j++){
            const int jj = j0 + j;
            const float* wr = Wih + (size_t) jj      *82 + 18 + kc*16;
            const float* wz = Wih + (size_t)(jj+ 64) *82 + 18 + kc*16;
            const float* wn = Wih + (size_t)(jj+128) *82 + 18 + kc*16;
            #pragma unroll
            for (int i=0;i<16;i++){
                ar[j] += ck[i]*wr[i]; az[j] += ck[i]*wz[i]; ain[j] += ck[i]*wn[i];
            }
        }
    }

    // h part: 4 chunks of 16 from LDS
    #pragma unroll
    for (int kc=0;kc<4;kc++){
        float hk[16];
        #pragma unroll
        for (int q=0;q<4;q++){
            float4 v = *(const float4*)&ct[lane][64 + kc*16 + q*4];
            hk[q*4+0]=v.x; hk[q*4+1]=v.y; hk[q*4+2]=v.z; hk[q*4+3]=v.w;
        }
        #pragma unroll
        for (int j=0;j<8;j++){
            const int jj = j0 + j;
            const float* wr = Whh + (size_t) jj      *HID + kc*16;
            const float* wz = Whh + (size_t)(jj+ 64) *HID + kc*16;
            const float* wn = Whh + (size_t)(jj+128) *HID + kc*16;
            #pragma unroll
            for (int i=0;i<16;i++){
                ar[j] += hk[i]*wr[i]; az[j] += hk[i]*wz[i]; ahn[j] += hk[i]*wn[i];
            }
        }
    }

    float xacc = 0.f;
    #pragma unroll
    for (int j=0;j<8;j++){
        const int jj = j0 + j;
        const float r = sigf(ar[j]);
        const float z = sigf(az[j]);
        const float n = tanhf_(ain[j] + r*ahn[j]);
        const float hold = ct[lane][64+jj];
        const float hp = (1.f - z)*n + z*hold;
        h_out[(size_t)jj*BN + node] = hp;
        xacc += hp * Wout[jj];
    }

    xs[w][lane] = xacc;
    __syncthreads();
    if (w == 0){
        float v = bout[0];
        #pragma unroll
        for (int q=0;q<8;q++) v += xs[q][lane];
        xn_out[node] = v;
    }
}

// ---------------- decoder step ----------------
__global__ __launch_bounds__(512, 4) void dec_step(
    const float* __restrict__ X,
    const float* __restrict__ Win, const float* __restrict__ bin,
    const float* __restrict__ Wih, const float* __restrict__ Whh,
    const float* __restrict__ bih, const float* __restrict__ bhh,
    const float* __restrict__ Wout, const float* __restrict__ bout,
    const float* __restrict__ h_in, float* __restrict__ h_out,
    const float* __restrict__ xn_in, float* __restrict__ xn_out,
    float* __restrict__ out, int t)
{
    __shared__ float ht[64][PADH];
    __shared__ float xs[8][64];

    const int lane = threadIdx.x & 63;
    int w = threadIdx.x >> 6;
    w = __builtin_amdgcn_readfirstlane(w);
    const int node = blockIdx.x*64 + lane;
    const int b    = node / NN;
    const int nloc = node - b*NN;

    const float* Xt = X + (size_t)(b*TT + HIST + t)*NN*FF;

    // stage h
    #pragma unroll
    for (int i=0;i<8;i++){
        const int k = w*8 + i;
        ht[lane][k] = h_in[(size_t)k*BN + node];
    }

    float x4[4];
    x4[0] = xn_in[node];
    x4[1] = Xt[nloc*FF + 13];
    x4[2] = Xt[nloc*FF + 14];
    x4[3] = Xt[nloc*FF + 15];
    __syncthreads();

    const int j0 = w*8;
    float ar[8], az[8], ain[8], ahn[8];
    #pragma unroll
    for (int j=0;j<8;j++){
        const int jj = j0 + j;
        ar[j]  = bih[jj]     + bhh[jj];
        az[j]  = bih[64+jj]  + bhh[64+jj];
        ain[j] = bih[128+jj];
        ahn[j] = bhh[128+jj];
    }

    // xin chunks computed on the fly (saves 64 VGPRs), then both GEMVs
    #pragma unroll
    for (int kc=0;kc<4;kc++){
        float xk[16];
        #pragma unroll
        for (int i=0;i<16;i++){
            const int k = kc*16 + i;
            xk[i] = bin[k] + x4[0]*Win[k] + x4[1]*Win[64+k]
                           + x4[2]*Win[128+k] + x4[3]*Win[192+k];
        }
        #pragma unroll
        for (int j=0;j<8;j++){
            const int jj = j0 + j;
            const float* wr = Wih + (size_t) jj      *HID + kc*16;
            const float* wz = Wih + (size_t)(jj+ 64) *HID + kc*16;
            const float* wn = Wih + (size_t)(jj+128) *HID + kc*16;
            #pragma unroll
            for (int i=0;i<16;i++){
                ar[j] += xk[i]*wr[i]; az[j] += xk[i]*wz[i]; ain[j] += xk[i]*wn[i];
            }
        }
    }

    #pragma unroll
    for (int kc=0;kc<4;kc++){
        float hk[16];
        #pragma unroll
        for (int q=0;q<4;q++){
            float4 v = *(const float4*)&ht[lane][kc*16 + q*4];
            hk[q*4+0]=v.x; hk[q*4+1]=v.y; hk[q*4+2]=v.z; hk[q*4+3]=v.w;
        }
        #pragma unroll
        for (int j=0;j<8;j++){
            const int jj = j0 + j;
            const float* wr = Whh + (size_t) jj      *HID + kc*16;
            const float* wz = Whh + (size_t)(jj+ 64) *HID + kc*16;
            const float* wn = Whh + (size_t)(jj+128) *HID + kc*16;
            #pragma unroll
            for (int i=0;i<16;i++){
                ar[j] += hk[i]*wr[i]; az[j] += hk[i]*wz[i]; ahn[j] += hk[i]*wn[i];
            }
        }
    }

    float xacc = 0.f;
    #pragma unroll
    for (int j=0;j<8;j++){
        const int jj = j0 + j;
        const float r = sigf(ar[j]);
        const float z = sigf(az[j]);
        const float n = tanhf_(ain[j] + r*ahn[j]);
        const float hold = ht[lane][jj];
        const float hp = (1.f - z)*n + z*hold;
        h_out[(size_t)jj*BN + node] = hp;
        xacc += hp * Wout[jj];
    }

    xs[w][lane] = xacc;
    __syncthreads();
    if (w == 0){
        float v = bout[0];
        #pragma unroll
        for (int q=0;q<8;q++) v += xs[q][lane];
        xn_out[node] = v;
        out[(size_t)(b*FC + t)*NN + nloc] = v;
    }
}

extern "C" void kernel_launch(void* const* d_in, const int* in_sizes, int n_in,
                              void* d_out, int out_size, void* d_ws, size_t ws_size,
                              hipStream_t stream)
{
    const float* X     = (const float*)d_in[0];
    const float* y     = (const float*)d_in[1];
    const int*   ei    = (const int*)  d_in[2];   // [2][E]; row 0 = src
    const float* ew    = (const float*)d_in[3];
    const float* W_rel = (const float*)d_in[4];
    const float* b_rel = (const float*)d_in[5];
    const float* W_root= (const float*)d_in[6];
    const float* eWih  = (const float*)d_in[7];
    const float* eWhh  = (const float*)d_in[8];
    const float* ebih  = (const float*)d_in[9];
    const float* ebhh  = (const float*)d_in[10];
    const float* eWout = (const float*)d_in[11];
    const float* ebout = (const float*)d_in[12];
    const float* dWin  = (const float*)d_in[13];
    const float* dbin  = (const float*)d_in[14];
    const float* dWih  = (const float*)d_in[15];
    const float* dWhh  = (const float*)d_in[16];
    const float* dbih  = (const float*)d_in[17];
    const float* dbhh  = (const float*)d_in[18];
    const float* dWout = (const float*)d_in[19];
    const float* dbout = (const float*)d_in[20];
    float* out = (float*)d_out;

    // workspace: static agg (24*17*BN = 52.2MB) + ping-pong h (2x8.19MB) + xn (2x128KB)
    float* aggs = (float*)d_ws;
    float* h0 = aggs + (size_t)24*17*BN;
    float* h1 = h0 + (size_t)BN*HID;
    float* x0 = h1 + (size_t)BN*HID;
    float* x1 = x0 + BN;

    hipMemsetAsync(h0, 0, (size_t)BN*HID*sizeof(float), stream);
    hipMemsetAsync(x0, 0, (size_t)BN*sizeof(float), stream);

    const int* esrc = ei;  // first E entries

    // hoisted static-feature aggregation for all encoder steps (parallel, once)
    agg_pre<<<dim3(BX,24), 256, 0, stream>>>(X, y, esrc, ew, aggs);

    float* hin = h0; float* hout = h1;
    float* xin = x0; float* xout = x1;

    for (int t=0; t<HIST; t++){
        enc_step<<<500, 512, 0, stream>>>(X, y, esrc, ew, aggs, W_rel, b_rel, W_root,
                                          eWih, eWhh, ebih, ebhh, eWout, ebout,
                                          hin, hout, xin, xout, t);
        float* tmp;
        tmp = hin; hin = hout; hout = tmp;
        tmp = xin; xin = xout; xout = tmp;
    }
    for (int t=0; t<FC; t++){
        dec_step<<<500, 512, 0, stream>>>(X, dWin, dbin, dWih, dWhh, dbih, dbhh,
                                          dWout, dbout, hin, hout, xin, xout, out, t);
        float* tmp;
        tmp = hin; hin = hout; hout = tmp;
        tmp = xin; xin = xout; xout = tmp;
    }
}